// Round 5
// baseline (130.171 us; speedup 1.0000x reference)
//
#include <hip/hip_runtime.h>
#include <math.h>

#define NJ 24
#define TPB 256
#define VPT 4
#define VPB (TPB * VPT)   // 1024 vertices per block
#define FK_BPB 8          // batches per FK block

__device__ __constant__ int PAR[NJ] = {-1,0,0,0,1,2,3,4,5,6,7,8,9,9,9,12,13,14,16,17,18,19,20,21};
// Root-first ancestor chain (including self), padded with -1.
__device__ __constant__ int CHAIN[NJ][9] = {
  {0,-1,-1,-1,-1,-1,-1,-1,-1},
  {0, 1,-1,-1,-1,-1,-1,-1,-1},
  {0, 2,-1,-1,-1,-1,-1,-1,-1},
  {0, 3,-1,-1,-1,-1,-1,-1,-1},
  {0, 1, 4,-1,-1,-1,-1,-1,-1},
  {0, 2, 5,-1,-1,-1,-1,-1,-1},
  {0, 3, 6,-1,-1,-1,-1,-1,-1},
  {0, 1, 4, 7,-1,-1,-1,-1,-1},
  {0, 2, 5, 8,-1,-1,-1,-1,-1},
  {0, 3, 6, 9,-1,-1,-1,-1,-1},
  {0, 1, 4, 7,10,-1,-1,-1,-1},
  {0, 2, 5, 8,11,-1,-1,-1,-1},
  {0, 3, 6, 9,12,-1,-1,-1,-1},
  {0, 3, 6, 9,13,-1,-1,-1,-1},
  {0, 3, 6, 9,14,-1,-1,-1,-1},
  {0, 3, 6, 9,12,15,-1,-1,-1},
  {0, 3, 6, 9,13,16,-1,-1,-1},
  {0, 3, 6, 9,14,17,-1,-1,-1},
  {0, 3, 6, 9,13,16,18,-1,-1},
  {0, 3, 6, 9,14,17,19,-1,-1},
  {0, 3, 6, 9,13,16,18,20,-1},
  {0, 3, 6, 9,14,17,19,21,-1},
  {0, 3, 6, 9,13,16,18,20,22},
  {0, 3, 6, 9,14,17,19,21,23},
};

// ---- device helpers ----

__device__ __forceinline__ void fk_local(const float* __restrict__ J_hat,
                                         const float* __restrict__ pose,
                                         int b, int j, float* __restrict__ L /*12*/)
{
  const float rx = pose[b * 72 + j * 3 + 0];
  const float ry = pose[b * 72 + j * 3 + 1];
  const float rz = pose[b * 72 + j * 3 + 2];
  const float theta = sqrtf(rx * rx + ry * ry + rz * rz) + 1e-8f;
  const float inv = 1.0f / theta;
  const float ux = rx * inv, uy = ry * inv, uz = rz * inv;
  const float c = cosf(theta), s = sinf(theta);
  const float ic = 1.0f - c;

  float tx = J_hat[j * 3 + 0];
  float ty = J_hat[j * 3 + 1];
  float tz = J_hat[j * 3 + 2];
  const int p = PAR[j];
  if (p >= 0) {
    tx -= J_hat[p * 3 + 0];
    ty -= J_hat[p * 3 + 1];
    tz -= J_hat[p * 3 + 2];
  }

  L[0]  = c + ic * ux * ux;
  L[1]  = ic * ux * uy - s * uz;
  L[2]  = ic * ux * uz + s * uy;
  L[3]  = tx;
  L[4]  = ic * uy * ux + s * uz;
  L[5]  = c + ic * uy * uy;
  L[6]  = ic * uy * uz - s * ux;
  L[7]  = ty;
  L[8]  = ic * uz * ux - s * uy;
  L[9]  = ic * uz * uy + s * ux;
  L[10] = c + ic * uz * uz;
  L[11] = tz;
}

__device__ __forceinline__ void fk_compose(const float (*__restrict__ Lc)[12],
                                           const float* __restrict__ J_hat,
                                           int j, float* __restrict__ g /*12*/)
{
#pragma unroll
  for (int k = 0; k < 12; k++) g[k] = Lc[0][k];
#pragma unroll
  for (int d = 1; d < 9; d++) {
    const int a = CHAIN[j][d];
    if (a >= 0) {
      float l[12];
#pragma unroll
      for (int k = 0; k < 12; k++) l[k] = Lc[a][k];
      float n[12];
#pragma unroll
      for (int r = 0; r < 3; r++) {
        const float gr0 = g[r * 4 + 0], gr1 = g[r * 4 + 1], gr2 = g[r * 4 + 2];
        n[r * 4 + 0] = gr0 * l[0] + gr1 * l[4] + gr2 * l[8];
        n[r * 4 + 1] = gr0 * l[1] + gr1 * l[5] + gr2 * l[9];
        n[r * 4 + 2] = gr0 * l[2] + gr1 * l[6] + gr2 * l[10];
        n[r * 4 + 3] = gr0 * l[3] + gr1 * l[7] + gr2 * l[11] + g[r * 4 + 3];
      }
#pragma unroll
      for (int k = 0; k < 12; k++) g[k] = n[k];
    }
  }
  // subtract rest-pose joint location: t' = t - R_g @ J_hat[j]
  const float jx = J_hat[j * 3 + 0], jy = J_hat[j * 3 + 1], jz = J_hat[j * 3 + 2];
  g[3]  -= g[0] * jx + g[1] * jy + g[2]  * jz;
  g[7]  -= g[4] * jx + g[5] * jy + g[6]  * jz;
  g[11] -= g[8] * jx + g[9] * jy + g[10] * jz;
}

// ---- kernel 1: forward kinematics, FK_BPB batches per block ----
__global__ __launch_bounds__(FK_BPB * 32) void smpl_fk_kernel(
    const float* __restrict__ J_hat,
    const float* __restrict__ pose,
    float* __restrict__ Gws,   // (B, 24, 12)
    int B)
{
  __shared__ __align__(16) float Lc[FK_BPB][NJ][12];
  const int lb = threadIdx.x >> 5;
  const int j  = threadIdx.x & 31;
  const int b  = blockIdx.x * FK_BPB + lb;
  const bool active = (j < NJ) && (b < B);

  if (active) {
    float L[12];
    fk_local(J_hat, pose, b, j, L);
#pragma unroll
    for (int k = 0; k < 12; k++) Lc[lb][j][k] = L[k];
  }
  __syncthreads();
  if (active) {
    float g[12];
    fk_compose(Lc[lb], J_hat, j, g);
    float* dst = Gws + (size_t)b * (NJ * 12) + j * 12;
#pragma unroll
    for (int k = 0; k < 12; k++) dst[k] = g[k];
  }
}

// ---- kernel 2 (primary): blend, G read via block-uniform (scalar) loads ----
__global__ __launch_bounds__(TPB) void smpl_blend_ws_kernel(
    const float* __restrict__ T_hat,
    const float* __restrict__ weights,
    const float* __restrict__ trans,
    const float* __restrict__ Gws,
    float* __restrict__ out,
    int V)
{
  const int b = blockIdx.y;
  const int tid = threadIdx.x;
  const int v0 = blockIdx.x * VPB + tid * VPT;
  if (v0 >= V) return;

  const float* __restrict__ Gb = Gws + (size_t)b * (NJ * 12);  // block-uniform
  const float t0 = trans[b * 3 + 0];
  const float t1 = trans[b * 3 + 1];
  const float t2 = trans[b * 3 + 2];
  float* __restrict__ outb = out + (size_t)b * V * 3;

  if (v0 + VPT <= V) {
    const float* __restrict__ wbase = weights + (size_t)v0 * 24;
    float acc[VPT][12];

#pragma unroll
    for (int jc = 0; jc < 6; jc++) {
      float4 w4[VPT];
#pragma unroll
      for (int i = 0; i < VPT; i++)
        w4[i] = *reinterpret_cast<const float4*>(wbase + i * 24 + jc * 4);
#pragma unroll
      for (int jj = 0; jj < 4; jj++) {
        const int j = jc * 4 + jj;
        // block-uniform addresses -> s_load into SGPRs, consumed directly by v_fma
        const float4 g0 = *reinterpret_cast<const float4*>(Gb + j * 12 + 0);
        const float4 g1 = *reinterpret_cast<const float4*>(Gb + j * 12 + 4);
        const float4 g2 = *reinterpret_cast<const float4*>(Gb + j * 12 + 8);
#pragma unroll
        for (int i = 0; i < VPT; i++) {
          const float w = (jj == 0) ? w4[i].x : (jj == 1) ? w4[i].y
                        : (jj == 2) ? w4[i].z : w4[i].w;
          if (jc == 0 && jj == 0) {
            acc[i][0]  = w * g0.x;  acc[i][1]  = w * g0.y;
            acc[i][2]  = w * g0.z;  acc[i][3]  = w * g0.w;
            acc[i][4]  = w * g1.x;  acc[i][5]  = w * g1.y;
            acc[i][6]  = w * g1.z;  acc[i][7]  = w * g1.w;
            acc[i][8]  = w * g2.x;  acc[i][9]  = w * g2.y;
            acc[i][10] = w * g2.z;  acc[i][11] = w * g2.w;
          } else {
            acc[i][0]  = fmaf(w, g0.x, acc[i][0]);
            acc[i][1]  = fmaf(w, g0.y, acc[i][1]);
            acc[i][2]  = fmaf(w, g0.z, acc[i][2]);
            acc[i][3]  = fmaf(w, g0.w, acc[i][3]);
            acc[i][4]  = fmaf(w, g1.x, acc[i][4]);
            acc[i][5]  = fmaf(w, g1.y, acc[i][5]);
            acc[i][6]  = fmaf(w, g1.z, acc[i][6]);
            acc[i][7]  = fmaf(w, g1.w, acc[i][7]);
            acc[i][8]  = fmaf(w, g2.x, acc[i][8]);
            acc[i][9]  = fmaf(w, g2.y, acc[i][9]);
            acc[i][10] = fmaf(w, g2.z, acc[i][10]);
            acc[i][11] = fmaf(w, g2.w, acc[i][11]);
          }
        }
      }
    }

    // T_hat: 12 contiguous floats, 16B-aligned (v0 % 4 == 0)
    float th[3 * VPT];
    const float4* tp = reinterpret_cast<const float4*>(T_hat + (size_t)v0 * 3);
#pragma unroll
    for (int q = 0; q < 3; q++) {
      const float4 t = tp[q];
      th[q * 4 + 0] = t.x; th[q * 4 + 1] = t.y;
      th[q * 4 + 2] = t.z; th[q * 4 + 3] = t.w;
    }

    float o[3 * VPT];
#pragma unroll
    for (int i = 0; i < VPT; i++) {
      const float x = th[i * 3 + 0], y = th[i * 3 + 1], z = th[i * 3 + 2];
      o[i * 3 + 0] = acc[i][0] * x + acc[i][1] * y + acc[i][2]  * z + acc[i][3]  + t0;
      o[i * 3 + 1] = acc[i][4] * x + acc[i][5] * y + acc[i][6]  * z + acc[i][7]  + t1;
      o[i * 3 + 2] = acc[i][8] * x + acc[i][9] * y + acc[i][10] * z + acc[i][11] + t2;
    }
    float4* op = reinterpret_cast<float4*>(outb + (size_t)v0 * 3);
#pragma unroll
    for (int q = 0; q < 3; q++)
      op[q] = make_float4(o[q * 4 + 0], o[q * 4 + 1], o[q * 4 + 2], o[q * 4 + 3]);
  } else {
    // tail: per-vertex scalar path (6890 % 4 == 2 -> last thread does 2)
    for (int v = v0; v < V; v++) {
      float acc[12];
#pragma unroll
      for (int k = 0; k < 12; k++) acc[k] = 0.0f;
      const float* wv = weights + (size_t)v * 24;
#pragma unroll
      for (int j = 0; j < NJ; j++) {
        const float w = wv[j];
#pragma unroll
        for (int k = 0; k < 12; k++) acc[k] = fmaf(w, Gb[j * 12 + k], acc[k]);
      }
      const float x = T_hat[v * 3 + 0], y = T_hat[v * 3 + 1], z = T_hat[v * 3 + 2];
      outb[v * 3 + 0] = acc[0] * x + acc[1] * y + acc[2]  * z + acc[3]  + t0;
      outb[v * 3 + 1] = acc[4] * x + acc[5] * y + acc[6]  * z + acc[7]  + t1;
      outb[v * 3 + 2] = acc[8] * x + acc[9] * y + acc[10] * z + acc[11] + t2;
    }
  }
}

// ---- fallback blend (ws too small): FK inline + LDS broadcast ----
__global__ __launch_bounds__(TPB) void smpl_blend_lds_kernel(
    const float* __restrict__ T_hat,
    const float* __restrict__ J_hat,
    const float* __restrict__ weights,
    const float* __restrict__ pose,
    const float* __restrict__ trans,
    float* __restrict__ out,
    int V)
{
  __shared__ __align__(16) float Lc[NJ][12];
  __shared__ __align__(16) float Gm[NJ][12];
  const int b = blockIdx.y;
  const int tid = threadIdx.x;

  if (tid < NJ) {
    float L[12];
    fk_local(J_hat, pose, b, tid, L);
#pragma unroll
    for (int k = 0; k < 12; k++) Lc[tid][k] = L[k];
  }
  __syncthreads();
  if (tid < NJ) {
    float g[12];
    fk_compose(Lc, J_hat, tid, g);
#pragma unroll
    for (int k = 0; k < 12; k++) Gm[tid][k] = g[k];
  }
  __syncthreads();

  const int v0 = blockIdx.x * VPB + tid * VPT;
  if (v0 >= V) return;

  const float t0 = trans[b * 3 + 0];
  const float t1 = trans[b * 3 + 1];
  const float t2 = trans[b * 3 + 2];
  float* __restrict__ outb = out + (size_t)b * V * 3;

  for (int v = v0; v < V && v < v0 + VPT; v++) {
    float acc[12];
#pragma unroll
    for (int k = 0; k < 12; k++) acc[k] = 0.0f;
    const float* wv = weights + (size_t)v * 24;
#pragma unroll
    for (int j = 0; j < NJ; j++) {
      const float w = wv[j];
#pragma unroll
      for (int k = 0; k < 12; k++) acc[k] = fmaf(w, Gm[j][k], acc[k]);
    }
    const float x = T_hat[v * 3 + 0], y = T_hat[v * 3 + 1], z = T_hat[v * 3 + 2];
    outb[v * 3 + 0] = acc[0] * x + acc[1] * y + acc[2]  * z + acc[3]  + t0;
    outb[v * 3 + 1] = acc[4] * x + acc[5] * y + acc[6]  * z + acc[7]  + t1;
    outb[v * 3 + 2] = acc[8] * x + acc[9] * y + acc[10] * z + acc[11] + t2;
  }
}

extern "C" void kernel_launch(void* const* d_in, const int* in_sizes, int n_in,
                              void* d_out, int out_size, void* d_ws, size_t ws_size,
                              hipStream_t stream) {
  const float* T_hat   = (const float*)d_in[0];
  const float* J_hat   = (const float*)d_in[1];
  const float* weights = (const float*)d_in[2];
  const float* pose    = (const float*)d_in[3];
  const float* trans   = (const float*)d_in[4];
  float* out = (float*)d_out;

  const int V = in_sizes[0] / 3;   // 6890
  const int B = in_sizes[3] / 72;  // 512

  const int nvchunks = (V + VPB - 1) / VPB;  // 7
  dim3 grid(nvchunks, B);

  const size_t ws_needed = (size_t)B * NJ * 12 * sizeof(float);  // 576 KB
  if (ws_size >= ws_needed) {
    float* Gws = (float*)d_ws;
    const int fkblocks = (B + FK_BPB - 1) / FK_BPB;  // 64
    smpl_fk_kernel<<<fkblocks, FK_BPB * 32, 0, stream>>>(J_hat, pose, Gws, B);
    smpl_blend_ws_kernel<<<grid, TPB, 0, stream>>>(
        T_hat, weights, trans, Gws, out, V);
  } else {
    smpl_blend_lds_kernel<<<grid, TPB, 0, stream>>>(
        T_hat, J_hat, weights, pose, trans, out, V);
  }
}

// Round 6
// 80.744 us; speedup vs baseline: 1.6121x; 1.6121x over previous
//
#include <hip/hip_runtime.h>
#include <math.h>

#define NJ 24
#define TPB 256
#define VPT 2
#define VPB (TPB * VPT)   // 512 vertices per block
#define FK_BPB 8          // batches per FK block

__device__ __constant__ int PAR[NJ] = {-1,0,0,0,1,2,3,4,5,6,7,8,9,9,9,12,13,14,16,17,18,19,20,21};
// Root-first ancestor chain (including self), padded with -1.
__device__ __constant__ int CHAIN[NJ][9] = {
  {0,-1,-1,-1,-1,-1,-1,-1,-1},
  {0, 1,-1,-1,-1,-1,-1,-1,-1},
  {0, 2,-1,-1,-1,-1,-1,-1,-1},
  {0, 3,-1,-1,-1,-1,-1,-1,-1},
  {0, 1, 4,-1,-1,-1,-1,-1,-1},
  {0, 2, 5,-1,-1,-1,-1,-1,-1},
  {0, 3, 6,-1,-1,-1,-1,-1,-1},
  {0, 1, 4, 7,-1,-1,-1,-1,-1},
  {0, 2, 5, 8,-1,-1,-1,-1,-1},
  {0, 3, 6, 9,-1,-1,-1,-1,-1},
  {0, 1, 4, 7,10,-1,-1,-1,-1},
  {0, 2, 5, 8,11,-1,-1,-1,-1},
  {0, 3, 6, 9,12,-1,-1,-1,-1},
  {0, 3, 6, 9,13,-1,-1,-1,-1},
  {0, 3, 6, 9,14,-1,-1,-1,-1},
  {0, 3, 6, 9,12,15,-1,-1,-1},
  {0, 3, 6, 9,13,16,-1,-1,-1},
  {0, 3, 6, 9,14,17,-1,-1,-1},
  {0, 3, 6, 9,13,16,18,-1,-1},
  {0, 3, 6, 9,14,17,19,-1,-1},
  {0, 3, 6, 9,13,16,18,20,-1},
  {0, 3, 6, 9,14,17,19,21,-1},
  {0, 3, 6, 9,13,16,18,20,22},
  {0, 3, 6, 9,14,17,19,21,23},
};

// ---- device helpers ----

__device__ __forceinline__ void fk_local(const float* __restrict__ J_hat,
                                         const float* __restrict__ pose,
                                         int b, int j, float* __restrict__ L /*12*/)
{
  const float rx = pose[b * 72 + j * 3 + 0];
  const float ry = pose[b * 72 + j * 3 + 1];
  const float rz = pose[b * 72 + j * 3 + 2];
  const float theta = sqrtf(rx * rx + ry * ry + rz * rz) + 1e-8f;
  const float inv = 1.0f / theta;
  const float ux = rx * inv, uy = ry * inv, uz = rz * inv;
  const float c = cosf(theta), s = sinf(theta);
  const float ic = 1.0f - c;

  float tx = J_hat[j * 3 + 0];
  float ty = J_hat[j * 3 + 1];
  float tz = J_hat[j * 3 + 2];
  const int p = PAR[j];
  if (p >= 0) {
    tx -= J_hat[p * 3 + 0];
    ty -= J_hat[p * 3 + 1];
    tz -= J_hat[p * 3 + 2];
  }

  L[0]  = c + ic * ux * ux;
  L[1]  = ic * ux * uy - s * uz;
  L[2]  = ic * ux * uz + s * uy;
  L[3]  = tx;
  L[4]  = ic * uy * ux + s * uz;
  L[5]  = c + ic * uy * uy;
  L[6]  = ic * uy * uz - s * ux;
  L[7]  = ty;
  L[8]  = ic * uz * ux - s * uy;
  L[9]  = ic * uz * uy + s * ux;
  L[10] = c + ic * uz * uz;
  L[11] = tz;
}

__device__ __forceinline__ void fk_compose(const float (*__restrict__ Lc)[12],
                                           const float* __restrict__ J_hat,
                                           int j, float* __restrict__ g /*12*/)
{
#pragma unroll
  for (int k = 0; k < 12; k++) g[k] = Lc[0][k];
#pragma unroll
  for (int d = 1; d < 9; d++) {
    const int a = CHAIN[j][d];
    if (a >= 0) {
      float l[12];
#pragma unroll
      for (int k = 0; k < 12; k++) l[k] = Lc[a][k];
      float n[12];
#pragma unroll
      for (int r = 0; r < 3; r++) {
        const float gr0 = g[r * 4 + 0], gr1 = g[r * 4 + 1], gr2 = g[r * 4 + 2];
        n[r * 4 + 0] = gr0 * l[0] + gr1 * l[4] + gr2 * l[8];
        n[r * 4 + 1] = gr0 * l[1] + gr1 * l[5] + gr2 * l[9];
        n[r * 4 + 2] = gr0 * l[2] + gr1 * l[6] + gr2 * l[10];
        n[r * 4 + 3] = gr0 * l[3] + gr1 * l[7] + gr2 * l[11] + g[r * 4 + 3];
      }
#pragma unroll
      for (int k = 0; k < 12; k++) g[k] = n[k];
    }
  }
  // subtract rest-pose joint location: t' = t - R_g @ J_hat[j]
  const float jx = J_hat[j * 3 + 0], jy = J_hat[j * 3 + 1], jz = J_hat[j * 3 + 2];
  g[3]  -= g[0] * jx + g[1] * jy + g[2]  * jz;
  g[7]  -= g[4] * jx + g[5] * jy + g[6]  * jz;
  g[11] -= g[8] * jx + g[9] * jy + g[10] * jz;
}

// ---- kernel 1: forward kinematics, FK_BPB batches per block ----
__global__ __launch_bounds__(FK_BPB * 32) void smpl_fk_kernel(
    const float* __restrict__ J_hat,
    const float* __restrict__ pose,
    float* __restrict__ Gws,   // (B, 24, 12)
    int B)
{
  __shared__ __align__(16) float Lc[FK_BPB][NJ][12];
  const int lb = threadIdx.x >> 5;
  const int j  = threadIdx.x & 31;
  const int b  = blockIdx.x * FK_BPB + lb;
  const bool active = (j < NJ) && (b < B);

  if (active) {
    float L[12];
    fk_local(J_hat, pose, b, j, L);
#pragma unroll
    for (int k = 0; k < 12; k++) Lc[lb][j][k] = L[k];
  }
  __syncthreads();
  if (active) {
    float g[12];
    fk_compose(Lc[lb], J_hat, j, g);
    float* dst = Gws + (size_t)b * (NJ * 12) + j * 12;
#pragma unroll
    for (int k = 0; k < 12; k++) dst[k] = g[k];
  }
}

// ---- kernel 2 (primary): blend. G broadcast from LDS, weights hoisted ----
__global__ __launch_bounds__(TPB) void smpl_blend_ws_kernel(
    const float* __restrict__ T_hat,
    const float* __restrict__ weights,
    const float* __restrict__ trans,
    const float* __restrict__ Gws,
    float* __restrict__ out,
    int V)
{
  __shared__ __align__(16) float4 Gs[NJ * 3];   // 24 joints x 3 rows of 4

  const int b = blockIdx.y;
  const int tid = threadIdx.x;

  if (tid < NJ * 3)
    Gs[tid] = reinterpret_cast<const float4*>(Gws + (size_t)b * (NJ * 12))[tid];
  __syncthreads();

  const int v0 = blockIdx.x * VPB + tid * VPT;
  if (v0 >= V) return;        // V even, VPT=2 -> only full pairs exist

  // ---- hoist ALL global loads: one vmcnt drain instead of six ----
  float4 w[12];               // 2 vertices x 24 weights
  const float4* wp = reinterpret_cast<const float4*>(weights + (size_t)v0 * 24);
#pragma unroll
  for (int q = 0; q < 12; q++) w[q] = wp[q];

  float th[6];                // 2 vertices x xyz (8B-aligned: v0 even)
  const float2* tp = reinterpret_cast<const float2*>(T_hat + (size_t)v0 * 3);
#pragma unroll
  for (int q = 0; q < 3; q++) {
    const float2 t = tp[q];
    th[q * 2 + 0] = t.x;
    th[q * 2 + 1] = t.y;
  }

  const float t0 = trans[b * 3 + 0];
  const float t1 = trans[b * 3 + 1];
  const float t2 = trans[b * 3 + 2];

  float acc[VPT][12];
#pragma unroll
  for (int i = 0; i < VPT; i++)
#pragma unroll
    for (int k = 0; k < 12; k++) acc[i][k] = 0.0f;

  // ---- j-loop: 3 broadcast ds_read_b128 + 24 FMA per joint ----
#pragma unroll
  for (int j = 0; j < NJ; j++) {
    const float4 g0 = Gs[j * 3 + 0];
    const float4 g1 = Gs[j * 3 + 1];
    const float4 g2 = Gs[j * 3 + 2];
#pragma unroll
    for (int i = 0; i < VPT; i++) {
      // j is compile-time constant here (loop fully unrolled) -> static index
      const float wj = reinterpret_cast<const float*>(&w[i * 6 + (j >> 2)])[j & 3];
      acc[i][0]  = fmaf(wj, g0.x, acc[i][0]);
      acc[i][1]  = fmaf(wj, g0.y, acc[i][1]);
      acc[i][2]  = fmaf(wj, g0.z, acc[i][2]);
      acc[i][3]  = fmaf(wj, g0.w, acc[i][3]);
      acc[i][4]  = fmaf(wj, g1.x, acc[i][4]);
      acc[i][5]  = fmaf(wj, g1.y, acc[i][5]);
      acc[i][6]  = fmaf(wj, g1.z, acc[i][6]);
      acc[i][7]  = fmaf(wj, g1.w, acc[i][7]);
      acc[i][8]  = fmaf(wj, g2.x, acc[i][8]);
      acc[i][9]  = fmaf(wj, g2.y, acc[i][9]);
      acc[i][10] = fmaf(wj, g2.z, acc[i][10]);
      acc[i][11] = fmaf(wj, g2.w, acc[i][11]);
    }
  }

  float o[3 * VPT];
#pragma unroll
  for (int i = 0; i < VPT; i++) {
    const float x = th[i * 3 + 0], y = th[i * 3 + 1], z = th[i * 3 + 2];
    o[i * 3 + 0] = acc[i][0] * x + acc[i][1] * y + acc[i][2]  * z + acc[i][3]  + t0;
    o[i * 3 + 1] = acc[i][4] * x + acc[i][5] * y + acc[i][6]  * z + acc[i][7]  + t1;
    o[i * 3 + 2] = acc[i][8] * x + acc[i][9] * y + acc[i][10] * z + acc[i][11] + t2;
  }
  float2* op = reinterpret_cast<float2*>(out + (size_t)b * V * 3 + (size_t)v0 * 3);
#pragma unroll
  for (int q = 0; q < 3; q++)
    op[q] = make_float2(o[q * 2 + 0], o[q * 2 + 1]);
}

// ---- fallback blend (ws too small): FK inline + LDS broadcast ----
__global__ __launch_bounds__(TPB) void smpl_blend_lds_kernel(
    const float* __restrict__ T_hat,
    const float* __restrict__ J_hat,
    const float* __restrict__ weights,
    const float* __restrict__ pose,
    const float* __restrict__ trans,
    float* __restrict__ out,
    int V)
{
  __shared__ __align__(16) float Lc[NJ][12];
  __shared__ __align__(16) float Gm[NJ][12];
  const int b = blockIdx.y;
  const int tid = threadIdx.x;

  if (tid < NJ) {
    float L[12];
    fk_local(J_hat, pose, b, tid, L);
#pragma unroll
    for (int k = 0; k < 12; k++) Lc[tid][k] = L[k];
  }
  __syncthreads();
  if (tid < NJ) {
    float g[12];
    fk_compose(Lc, J_hat, tid, g);
#pragma unroll
    for (int k = 0; k < 12; k++) Gm[tid][k] = g[k];
  }
  __syncthreads();

  const int v0 = blockIdx.x * VPB + tid * VPT;
  if (v0 >= V) return;

  const float t0 = trans[b * 3 + 0];
  const float t1 = trans[b * 3 + 1];
  const float t2 = trans[b * 3 + 2];
  float* __restrict__ outb = out + (size_t)b * V * 3;

  for (int v = v0; v < V && v < v0 + VPT; v++) {
    float acc[12];
#pragma unroll
    for (int k = 0; k < 12; k++) acc[k] = 0.0f;
    const float* wv = weights + (size_t)v * 24;
#pragma unroll
    for (int j = 0; j < NJ; j++) {
      const float w = wv[j];
#pragma unroll
      for (int k = 0; k < 12; k++) acc[k] = fmaf(w, Gm[j][k], acc[k]);
    }
    const float x = T_hat[v * 3 + 0], y = T_hat[v * 3 + 1], z = T_hat[v * 3 + 2];
    outb[v * 3 + 0] = acc[0] * x + acc[1] * y + acc[2]  * z + acc[3]  + t0;
    outb[v * 3 + 1] = acc[4] * x + acc[5] * y + acc[6]  * z + acc[7]  + t1;
    outb[v * 3 + 2] = acc[8] * x + acc[9] * y + acc[10] * z + acc[11] + t2;
  }
}

extern "C" void kernel_launch(void* const* d_in, const int* in_sizes, int n_in,
                              void* d_out, int out_size, void* d_ws, size_t ws_size,
                              hipStream_t stream) {
  const float* T_hat   = (const float*)d_in[0];
  const float* J_hat   = (const float*)d_in[1];
  const float* weights = (const float*)d_in[2];
  const float* pose    = (const float*)d_in[3];
  const float* trans   = (const float*)d_in[4];
  float* out = (float*)d_out;

  const int V = in_sizes[0] / 3;   // 6890
  const int B = in_sizes[3] / 72;  // 512

  const int nvchunks = (V + VPB - 1) / VPB;  // 14
  dim3 grid(nvchunks, B);

  const size_t ws_needed = (size_t)B * NJ * 12 * sizeof(float);  // 576 KB
  if (ws_size >= ws_needed) {
    float* Gws = (float*)d_ws;
    const int fkblocks = (B + FK_BPB - 1) / FK_BPB;  // 64
    smpl_fk_kernel<<<fkblocks, FK_BPB * 32, 0, stream>>>(J_hat, pose, Gws, B);
    smpl_blend_ws_kernel<<<grid, TPB, 0, stream>>>(
        T_hat, weights, trans, Gws, out, V);
  } else {
    smpl_blend_lds_kernel<<<grid, TPB, 0, stream>>>(
        T_hat, J_hat, weights, pose, trans, out, V);
  }
}

// Round 7
// 79.219 us; speedup vs baseline: 1.6432x; 1.0193x over previous
//
#include <hip/hip_runtime.h>
#include <math.h>

#define NJ 24
#define TPB 256
#define VPT 2
#define VPB (TPB * VPT)   // 512 vertices per block
#define BPT 4             // batches per blend block (sequential inner loop)
#define FK_BPB 8          // batches per FK block

__device__ __constant__ int PAR[NJ] = {-1,0,0,0,1,2,3,4,5,6,7,8,9,9,9,12,13,14,16,17,18,19,20,21};
// Root-first ancestor chain (including self), padded with -1.
__device__ __constant__ int CHAIN[NJ][9] = {
  {0,-1,-1,-1,-1,-1,-1,-1,-1},
  {0, 1,-1,-1,-1,-1,-1,-1,-1},
  {0, 2,-1,-1,-1,-1,-1,-1,-1},
  {0, 3,-1,-1,-1,-1,-1,-1,-1},
  {0, 1, 4,-1,-1,-1,-1,-1,-1},
  {0, 2, 5,-1,-1,-1,-1,-1,-1},
  {0, 3, 6,-1,-1,-1,-1,-1,-1},
  {0, 1, 4, 7,-1,-1,-1,-1,-1},
  {0, 2, 5, 8,-1,-1,-1,-1,-1},
  {0, 3, 6, 9,-1,-1,-1,-1,-1},
  {0, 1, 4, 7,10,-1,-1,-1,-1},
  {0, 2, 5, 8,11,-1,-1,-1,-1},
  {0, 3, 6, 9,12,-1,-1,-1,-1},
  {0, 3, 6, 9,13,-1,-1,-1,-1},
  {0, 3, 6, 9,14,-1,-1,-1,-1},
  {0, 3, 6, 9,12,15,-1,-1,-1},
  {0, 3, 6, 9,13,16,-1,-1,-1},
  {0, 3, 6, 9,14,17,-1,-1,-1},
  {0, 3, 6, 9,13,16,18,-1,-1},
  {0, 3, 6, 9,14,17,19,-1,-1},
  {0, 3, 6, 9,13,16,18,20,-1},
  {0, 3, 6, 9,14,17,19,21,-1},
  {0, 3, 6, 9,13,16,18,20,22},
  {0, 3, 6, 9,14,17,19,21,23},
};

// ---- device helpers ----

__device__ __forceinline__ void fk_local(const float* __restrict__ J_hat,
                                         const float* __restrict__ pose,
                                         int b, int j, float* __restrict__ L /*12*/)
{
  const float rx = pose[b * 72 + j * 3 + 0];
  const float ry = pose[b * 72 + j * 3 + 1];
  const float rz = pose[b * 72 + j * 3 + 2];
  const float theta = sqrtf(rx * rx + ry * ry + rz * rz) + 1e-8f;
  const float inv = 1.0f / theta;
  const float ux = rx * inv, uy = ry * inv, uz = rz * inv;
  const float c = cosf(theta), s = sinf(theta);
  const float ic = 1.0f - c;

  float tx = J_hat[j * 3 + 0];
  float ty = J_hat[j * 3 + 1];
  float tz = J_hat[j * 3 + 2];
  const int p = PAR[j];
  if (p >= 0) {
    tx -= J_hat[p * 3 + 0];
    ty -= J_hat[p * 3 + 1];
    tz -= J_hat[p * 3 + 2];
  }

  L[0]  = c + ic * ux * ux;
  L[1]  = ic * ux * uy - s * uz;
  L[2]  = ic * ux * uz + s * uy;
  L[3]  = tx;
  L[4]  = ic * uy * ux + s * uz;
  L[5]  = c + ic * uy * uy;
  L[6]  = ic * uy * uz - s * ux;
  L[7]  = ty;
  L[8]  = ic * uz * ux - s * uy;
  L[9]  = ic * uz * uy + s * ux;
  L[10] = c + ic * uz * uz;
  L[11] = tz;
}

__device__ __forceinline__ void fk_compose(const float (*__restrict__ Lc)[12],
                                           const float* __restrict__ J_hat,
                                           int j, float* __restrict__ g /*12*/)
{
#pragma unroll
  for (int k = 0; k < 12; k++) g[k] = Lc[0][k];
#pragma unroll
  for (int d = 1; d < 9; d++) {
    const int a = CHAIN[j][d];
    if (a >= 0) {
      float l[12];
#pragma unroll
      for (int k = 0; k < 12; k++) l[k] = Lc[a][k];
      float n[12];
#pragma unroll
      for (int r = 0; r < 3; r++) {
        const float gr0 = g[r * 4 + 0], gr1 = g[r * 4 + 1], gr2 = g[r * 4 + 2];
        n[r * 4 + 0] = gr0 * l[0] + gr1 * l[4] + gr2 * l[8];
        n[r * 4 + 1] = gr0 * l[1] + gr1 * l[5] + gr2 * l[9];
        n[r * 4 + 2] = gr0 * l[2] + gr1 * l[6] + gr2 * l[10];
        n[r * 4 + 3] = gr0 * l[3] + gr1 * l[7] + gr2 * l[11] + g[r * 4 + 3];
      }
#pragma unroll
      for (int k = 0; k < 12; k++) g[k] = n[k];
    }
  }
  // subtract rest-pose joint location: t' = t - R_g @ J_hat[j]
  const float jx = J_hat[j * 3 + 0], jy = J_hat[j * 3 + 1], jz = J_hat[j * 3 + 2];
  g[3]  -= g[0] * jx + g[1] * jy + g[2]  * jz;
  g[7]  -= g[4] * jx + g[5] * jy + g[6]  * jz;
  g[11] -= g[8] * jx + g[9] * jy + g[10] * jz;
}

// ---- kernel 1: forward kinematics, FK_BPB batches per block ----
__global__ __launch_bounds__(FK_BPB * 32) void smpl_fk_kernel(
    const float* __restrict__ J_hat,
    const float* __restrict__ pose,
    float* __restrict__ Gws,   // (B, 24, 12)
    int B)
{
  __shared__ __align__(16) float Lc[FK_BPB][NJ][12];
  const int lb = threadIdx.x >> 5;
  const int j  = threadIdx.x & 31;
  const int b  = blockIdx.x * FK_BPB + lb;
  const bool active = (j < NJ) && (b < B);

  if (active) {
    float L[12];
    fk_local(J_hat, pose, b, j, L);
#pragma unroll
    for (int k = 0; k < 12; k++) Lc[lb][j][k] = L[k];
  }
  __syncthreads();
  if (active) {
    float g[12];
    fk_compose(Lc[lb], J_hat, j, g);
    float* dst = Gws + (size_t)b * (NJ * 12) + j * 12;
#pragma unroll
    for (int k = 0; k < 12; k++) dst[k] = g[k];
  }
}

// ---- kernel 2 (primary): blend. BPT batches per block; weights loaded
// once per thread and reused across the sequential batch loop. ----
__global__ __launch_bounds__(TPB) void smpl_blend_ws_kernel(
    const float* __restrict__ T_hat,
    const float* __restrict__ weights,
    const float* __restrict__ trans,
    const float* __restrict__ Gws,
    float* __restrict__ out,
    int V)
{
  __shared__ __align__(16) float4 Gs[BPT * NJ * 3];   // 4 batches x 72 float4

  const int b0 = blockIdx.y * BPT;
  const int tid = threadIdx.x;

  // stage 4 batches' G (288 float4) with 256 threads
  {
    const float4* src = reinterpret_cast<const float4*>(Gws + (size_t)b0 * (NJ * 12));
    Gs[tid] = src[tid];
    if (tid < BPT * NJ * 3 - TPB) Gs[TPB + tid] = src[TPB + tid];
  }
  __syncthreads();

  const int v0 = blockIdx.x * VPB + tid * VPT;
  if (v0 >= V) return;        // V even, VPT=2 -> only full pairs exist

  // ---- one-time loads: weights + T_hat (single vmcnt drain) ----
  float4 w[12];               // 2 vertices x 24 weights
  const float4* wp = reinterpret_cast<const float4*>(weights + (size_t)v0 * 24);
#pragma unroll
  for (int q = 0; q < 12; q++) w[q] = wp[q];

  float th[6];                // 2 vertices x xyz (8B-aligned: v0 even)
  const float2* tp = reinterpret_cast<const float2*>(T_hat + (size_t)v0 * 3);
#pragma unroll
  for (int q = 0; q < 3; q++) {
    const float2 t = tp[q];
    th[q * 2 + 0] = t.x;
    th[q * 2 + 1] = t.y;
  }

  // ---- sequential batch loop: do NOT unroll (keeps VGPR bounded) ----
#pragma unroll 1
  for (int bi = 0; bi < BPT; bi++) {
    const int b = b0 + bi;
    const float4* __restrict__ Gb = &Gs[bi * NJ * 3];

    float acc[VPT][12];
#pragma unroll
    for (int i = 0; i < VPT; i++)
#pragma unroll
      for (int k = 0; k < 12; k++) acc[i][k] = 0.0f;

#pragma unroll
    for (int j = 0; j < NJ; j++) {
      const float4 g0 = Gb[j * 3 + 0];
      const float4 g1 = Gb[j * 3 + 1];
      const float4 g2 = Gb[j * 3 + 2];
#pragma unroll
      for (int i = 0; i < VPT; i++) {
        // j compile-time constant (inner unroll) -> static register select
        const float wj = reinterpret_cast<const float*>(&w[i * 6 + (j >> 2)])[j & 3];
        acc[i][0]  = fmaf(wj, g0.x, acc[i][0]);
        acc[i][1]  = fmaf(wj, g0.y, acc[i][1]);
        acc[i][2]  = fmaf(wj, g0.z, acc[i][2]);
        acc[i][3]  = fmaf(wj, g0.w, acc[i][3]);
        acc[i][4]  = fmaf(wj, g1.x, acc[i][4]);
        acc[i][5]  = fmaf(wj, g1.y, acc[i][5]);
        acc[i][6]  = fmaf(wj, g1.z, acc[i][6]);
        acc[i][7]  = fmaf(wj, g1.w, acc[i][7]);
        acc[i][8]  = fmaf(wj, g2.x, acc[i][8]);
        acc[i][9]  = fmaf(wj, g2.y, acc[i][9]);
        acc[i][10] = fmaf(wj, g2.z, acc[i][10]);
        acc[i][11] = fmaf(wj, g2.w, acc[i][11]);
      }
    }

    const float t0 = trans[b * 3 + 0];   // block-uniform -> s_load
    const float t1 = trans[b * 3 + 1];
    const float t2 = trans[b * 3 + 2];

    float o[3 * VPT];
#pragma unroll
    for (int i = 0; i < VPT; i++) {
      const float x = th[i * 3 + 0], y = th[i * 3 + 1], z = th[i * 3 + 2];
      o[i * 3 + 0] = acc[i][0] * x + acc[i][1] * y + acc[i][2]  * z + acc[i][3]  + t0;
      o[i * 3 + 1] = acc[i][4] * x + acc[i][5] * y + acc[i][6]  * z + acc[i][7]  + t1;
      o[i * 3 + 2] = acc[i][8] * x + acc[i][9] * y + acc[i][10] * z + acc[i][11] + t2;
    }
    float2* op = reinterpret_cast<float2*>(out + ((size_t)b * V + v0) * 3);
#pragma unroll
    for (int q = 0; q < 3; q++)
      op[q] = make_float2(o[q * 2 + 0], o[q * 2 + 1]);
  }
}

// ---- fallback blend (ws too small): FK inline + LDS broadcast ----
__global__ __launch_bounds__(TPB) void smpl_blend_lds_kernel(
    const float* __restrict__ T_hat,
    const float* __restrict__ J_hat,
    const float* __restrict__ weights,
    const float* __restrict__ pose,
    const float* __restrict__ trans,
    float* __restrict__ out,
    int V)
{
  __shared__ __align__(16) float Lc[NJ][12];
  __shared__ __align__(16) float Gm[NJ][12];
  const int b = blockIdx.y;
  const int tid = threadIdx.x;

  if (tid < NJ) {
    float L[12];
    fk_local(J_hat, pose, b, tid, L);
#pragma unroll
    for (int k = 0; k < 12; k++) Lc[tid][k] = L[k];
  }
  __syncthreads();
  if (tid < NJ) {
    float g[12];
    fk_compose(Lc, J_hat, tid, g);
#pragma unroll
    for (int k = 0; k < 12; k++) Gm[tid][k] = g[k];
  }
  __syncthreads();

  const int v0 = blockIdx.x * VPB + tid * VPT;
  if (v0 >= V) return;

  const float t0 = trans[b * 3 + 0];
  const float t1 = trans[b * 3 + 1];
  const float t2 = trans[b * 3 + 2];
  float* __restrict__ outb = out + (size_t)b * V * 3;

  for (int v = v0; v < V && v < v0 + VPT; v++) {
    float acc[12];
#pragma unroll
    for (int k = 0; k < 12; k++) acc[k] = 0.0f;
    const float* wv = weights + (size_t)v * 24;
#pragma unroll
    for (int j = 0; j < NJ; j++) {
      const float w = wv[j];
#pragma unroll
      for (int k = 0; k < 12; k++) acc[k] = fmaf(w, Gm[j][k], acc[k]);
    }
    const float x = T_hat[v * 3 + 0], y = T_hat[v * 3 + 1], z = T_hat[v * 3 + 2];
    outb[v * 3 + 0] = acc[0] * x + acc[1] * y + acc[2]  * z + acc[3]  + t0;
    outb[v * 3 + 1] = acc[4] * x + acc[5] * y + acc[6]  * z + acc[7]  + t1;
    outb[v * 3 + 2] = acc[8] * x + acc[9] * y + acc[10] * z + acc[11] + t2;
  }
}

extern "C" void kernel_launch(void* const* d_in, const int* in_sizes, int n_in,
                              void* d_out, int out_size, void* d_ws, size_t ws_size,
                              hipStream_t stream) {
  const float* T_hat   = (const float*)d_in[0];
  const float* J_hat   = (const float*)d_in[1];
  const float* weights = (const float*)d_in[2];
  const float* pose    = (const float*)d_in[3];
  const float* trans   = (const float*)d_in[4];
  float* out = (float*)d_out;

  const int V = in_sizes[0] / 3;   // 6890
  const int B = in_sizes[3] / 72;  // 512

  const int nvchunks = (V + VPB - 1) / VPB;  // 14

  const size_t ws_needed = (size_t)B * NJ * 12 * sizeof(float);  // 576 KB
  if (ws_size >= ws_needed && (B % BPT) == 0) {
    float* Gws = (float*)d_ws;
    const int fkblocks = (B + FK_BPB - 1) / FK_BPB;  // 64
    smpl_fk_kernel<<<fkblocks, FK_BPB * 32, 0, stream>>>(J_hat, pose, Gws, B);
    dim3 grid(nvchunks, B / BPT);  // (14, 128)
    smpl_blend_ws_kernel<<<grid, TPB, 0, stream>>>(
        T_hat, weights, trans, Gws, out, V);
  } else {
    dim3 grid(nvchunks, B);
    smpl_blend_lds_kernel<<<grid, TPB, 0, stream>>>(
        T_hat, J_hat, weights, pose, trans, out, V);
  }
}

// Round 8
// 58.113 us; speedup vs baseline: 2.2400x; 1.3632x over previous
//
#include <hip/hip_runtime.h>
#include <math.h>

#define NJ 24
#define TPB 256
#define BPT 4             // batches per blend block (sequential inner loop)
#define FK_BPB 8          // batches per FK block

__device__ __constant__ int PAR[NJ] = {-1,0,0,0,1,2,3,4,5,6,7,8,9,9,9,12,13,14,16,17,18,19,20,21};
// Root-first ancestor chain (including self), padded with -1.
__device__ __constant__ int CHAIN[NJ][9] = {
  {0,-1,-1,-1,-1,-1,-1,-1,-1},
  {0, 1,-1,-1,-1,-1,-1,-1,-1},
  {0, 2,-1,-1,-1,-1,-1,-1,-1},
  {0, 3,-1,-1,-1,-1,-1,-1,-1},
  {0, 1, 4,-1,-1,-1,-1,-1,-1},
  {0, 2, 5,-1,-1,-1,-1,-1,-1},
  {0, 3, 6,-1,-1,-1,-1,-1,-1},
  {0, 1, 4, 7,-1,-1,-1,-1,-1},
  {0, 2, 5, 8,-1,-1,-1,-1,-1},
  {0, 3, 6, 9,-1,-1,-1,-1,-1},
  {0, 1, 4, 7,10,-1,-1,-1,-1},
  {0, 2, 5, 8,11,-1,-1,-1,-1},
  {0, 3, 6, 9,12,-1,-1,-1,-1},
  {0, 3, 6, 9,13,-1,-1,-1,-1},
  {0, 3, 6, 9,14,-1,-1,-1,-1},
  {0, 3, 6, 9,12,15,-1,-1,-1},
  {0, 3, 6, 9,13,16,-1,-1,-1},
  {0, 3, 6, 9,14,17,-1,-1,-1},
  {0, 3, 6, 9,13,16,18,-1,-1},
  {0, 3, 6, 9,14,17,19,-1,-1},
  {0, 3, 6, 9,13,16,18,20,-1},
  {0, 3, 6, 9,14,17,19,21,-1},
  {0, 3, 6, 9,13,16,18,20,22},
  {0, 3, 6, 9,14,17,19,21,23},
};

// ---- device helpers ----

__device__ __forceinline__ void fk_local(const float* __restrict__ J_hat,
                                         const float* __restrict__ pose,
                                         int b, int j, float* __restrict__ L /*12*/)
{
  const float rx = pose[b * 72 + j * 3 + 0];
  const float ry = pose[b * 72 + j * 3 + 1];
  const float rz = pose[b * 72 + j * 3 + 2];
  const float theta = sqrtf(rx * rx + ry * ry + rz * rz) + 1e-8f;
  const float inv = 1.0f / theta;
  const float ux = rx * inv, uy = ry * inv, uz = rz * inv;
  const float c = cosf(theta), s = sinf(theta);
  const float ic = 1.0f - c;

  float tx = J_hat[j * 3 + 0];
  float ty = J_hat[j * 3 + 1];
  float tz = J_hat[j * 3 + 2];
  const int p = PAR[j];
  if (p >= 0) {
    tx -= J_hat[p * 3 + 0];
    ty -= J_hat[p * 3 + 1];
    tz -= J_hat[p * 3 + 2];
  }

  L[0]  = c + ic * ux * ux;
  L[1]  = ic * ux * uy - s * uz;
  L[2]  = ic * ux * uz + s * uy;
  L[3]  = tx;
  L[4]  = ic * uy * ux + s * uz;
  L[5]  = c + ic * uy * uy;
  L[6]  = ic * uy * uz - s * ux;
  L[7]  = ty;
  L[8]  = ic * uz * ux - s * uy;
  L[9]  = ic * uz * uy + s * ux;
  L[10] = c + ic * uz * uz;
  L[11] = tz;
}

__device__ __forceinline__ void fk_compose(const float (*__restrict__ Lc)[12],
                                           const float* __restrict__ J_hat,
                                           int j, float* __restrict__ g /*12*/)
{
#pragma unroll
  for (int k = 0; k < 12; k++) g[k] = Lc[0][k];
#pragma unroll
  for (int d = 1; d < 9; d++) {
    const int a = CHAIN[j][d];
    if (a >= 0) {
      float l[12];
#pragma unroll
      for (int k = 0; k < 12; k++) l[k] = Lc[a][k];
      float n[12];
#pragma unroll
      for (int r = 0; r < 3; r++) {
        const float gr0 = g[r * 4 + 0], gr1 = g[r * 4 + 1], gr2 = g[r * 4 + 2];
        n[r * 4 + 0] = gr0 * l[0] + gr1 * l[4] + gr2 * l[8];
        n[r * 4 + 1] = gr0 * l[1] + gr1 * l[5] + gr2 * l[9];
        n[r * 4 + 2] = gr0 * l[2] + gr1 * l[6] + gr2 * l[10];
        n[r * 4 + 3] = gr0 * l[3] + gr1 * l[7] + gr2 * l[11] + g[r * 4 + 3];
      }
#pragma unroll
      for (int k = 0; k < 12; k++) g[k] = n[k];
    }
  }
  // subtract rest-pose joint location: t' = t - R_g @ J_hat[j]
  const float jx = J_hat[j * 3 + 0], jy = J_hat[j * 3 + 1], jz = J_hat[j * 3 + 2];
  g[3]  -= g[0] * jx + g[1] * jy + g[2]  * jz;
  g[7]  -= g[4] * jx + g[5] * jy + g[6]  * jz;
  g[11] -= g[8] * jx + g[9] * jy + g[10] * jz;
}

// ---- kernel 1: forward kinematics, FK_BPB batches per block ----
__global__ __launch_bounds__(FK_BPB * 32) void smpl_fk_kernel(
    const float* __restrict__ J_hat,
    const float* __restrict__ pose,
    float* __restrict__ Gws,   // (B, 24, 12)
    int B)
{
  __shared__ __align__(16) float Lc[FK_BPB][NJ][12];
  const int lb = threadIdx.x >> 5;
  const int j  = threadIdx.x & 31;
  const int b  = blockIdx.x * FK_BPB + lb;
  const bool active = (j < NJ) && (b < B);

  if (active) {
    float L[12];
    fk_local(J_hat, pose, b, j, L);
#pragma unroll
    for (int k = 0; k < 12; k++) Lc[lb][j][k] = L[k];
  }
  __syncthreads();
  if (active) {
    float g[12];
    fk_compose(Lc[lb], J_hat, j, g);
    float* dst = Gws + (size_t)b * (NJ * 12) + j * 12;
#pragma unroll
    for (int k = 0; k < 12; k++) dst[k] = g[k];
  }
}

// ---- kernel 2 (primary): blend, VPT=1, BPT batches per block ----
// Minimal live set (~66 VGPR) to maximize resident waves; weights held in
// registers across the sequential 4-batch loop; G broadcast from LDS.
__global__ __launch_bounds__(TPB) void smpl_blend_ws_kernel(
    const float* __restrict__ T_hat,
    const float* __restrict__ weights,
    const float* __restrict__ trans,
    const float* __restrict__ Gws,
    float* __restrict__ out,
    int V)
{
  __shared__ __align__(16) float4 Gs[BPT * NJ * 3];   // 288 float4 = 4.6 KB

  const int b0 = blockIdx.y * BPT;
  const int tid = threadIdx.x;

  // stage 4 batches' G (288 float4) with 256 threads
  {
    const float4* src = reinterpret_cast<const float4*>(Gws + (size_t)b0 * (NJ * 12));
    Gs[tid] = src[tid];
    if (tid < BPT * NJ * 3 - TPB) Gs[TPB + tid] = src[TPB + tid];
  }
  __syncthreads();

  const int v = blockIdx.x * TPB + tid;
  if (v >= V) return;

  // ---- one-time loads: 24 weights + T_hat xyz (single drain) ----
  float w[24];
  const float4* wp = reinterpret_cast<const float4*>(weights + (size_t)v * 24);
#pragma unroll
  for (int q = 0; q < 6; q++) {
    const float4 t = wp[q];
    w[q * 4 + 0] = t.x; w[q * 4 + 1] = t.y;
    w[q * 4 + 2] = t.z; w[q * 4 + 3] = t.w;
  }
  const float x = T_hat[v * 3 + 0];
  const float y = T_hat[v * 3 + 1];
  const float z = T_hat[v * 3 + 2];

  // ---- sequential batch loop: do NOT unroll (keeps VGPR bounded) ----
#pragma unroll 1
  for (int bi = 0; bi < BPT; bi++) {
    const int b = b0 + bi;
    const float4* __restrict__ Gb = &Gs[bi * NJ * 3];

    float acc[12];
#pragma unroll
    for (int j = 0; j < NJ; j++) {
      const float4 g0 = Gb[j * 3 + 0];
      const float4 g1 = Gb[j * 3 + 1];
      const float4 g2 = Gb[j * 3 + 2];
      const float wj = w[j];
      if (j == 0) {
        acc[0]  = wj * g0.x;  acc[1]  = wj * g0.y;
        acc[2]  = wj * g0.z;  acc[3]  = wj * g0.w;
        acc[4]  = wj * g1.x;  acc[5]  = wj * g1.y;
        acc[6]  = wj * g1.z;  acc[7]  = wj * g1.w;
        acc[8]  = wj * g2.x;  acc[9]  = wj * g2.y;
        acc[10] = wj * g2.z;  acc[11] = wj * g2.w;
      } else {
        acc[0]  = fmaf(wj, g0.x, acc[0]);
        acc[1]  = fmaf(wj, g0.y, acc[1]);
        acc[2]  = fmaf(wj, g0.z, acc[2]);
        acc[3]  = fmaf(wj, g0.w, acc[3]);
        acc[4]  = fmaf(wj, g1.x, acc[4]);
        acc[5]  = fmaf(wj, g1.y, acc[5]);
        acc[6]  = fmaf(wj, g1.z, acc[6]);
        acc[7]  = fmaf(wj, g1.w, acc[7]);
        acc[8]  = fmaf(wj, g2.x, acc[8]);
        acc[9]  = fmaf(wj, g2.y, acc[9]);
        acc[10] = fmaf(wj, g2.z, acc[10]);
        acc[11] = fmaf(wj, g2.w, acc[11]);
      }
    }

    const float t0 = trans[b * 3 + 0];   // block-uniform -> s_load
    const float t1 = trans[b * 3 + 1];
    const float t2 = trans[b * 3 + 2];

    float* op = out + ((size_t)b * V + v) * 3;
    op[0] = acc[0] * x + acc[1] * y + acc[2]  * z + acc[3]  + t0;
    op[1] = acc[4] * x + acc[5] * y + acc[6]  * z + acc[7]  + t1;
    op[2] = acc[8] * x + acc[9] * y + acc[10] * z + acc[11] + t2;
  }
}

// ---- fallback blend (ws too small): FK inline + LDS broadcast, VPT=1 ----
__global__ __launch_bounds__(TPB) void smpl_blend_lds_kernel(
    const float* __restrict__ T_hat,
    const float* __restrict__ J_hat,
    const float* __restrict__ weights,
    const float* __restrict__ pose,
    const float* __restrict__ trans,
    float* __restrict__ out,
    int V)
{
  __shared__ __align__(16) float Lc[NJ][12];
  __shared__ __align__(16) float Gm[NJ][12];
  const int b = blockIdx.y;
  const int tid = threadIdx.x;

  if (tid < NJ) {
    float L[12];
    fk_local(J_hat, pose, b, tid, L);
#pragma unroll
    for (int k = 0; k < 12; k++) Lc[tid][k] = L[k];
  }
  __syncthreads();
  if (tid < NJ) {
    float g[12];
    fk_compose(Lc, J_hat, tid, g);
#pragma unroll
    for (int k = 0; k < 12; k++) Gm[tid][k] = g[k];
  }
  __syncthreads();

  const int v = blockIdx.x * TPB + tid;
  if (v >= V) return;

  float acc[12];
#pragma unroll
  for (int k = 0; k < 12; k++) acc[k] = 0.0f;
  const float* wv = weights + (size_t)v * 24;
#pragma unroll
  for (int j = 0; j < NJ; j++) {
    const float wj = wv[j];
#pragma unroll
    for (int k = 0; k < 12; k++) acc[k] = fmaf(wj, Gm[j][k], acc[k]);
  }
  const float x = T_hat[v * 3 + 0], y = T_hat[v * 3 + 1], z = T_hat[v * 3 + 2];
  float* op = out + ((size_t)b * V + v) * 3;
  op[0] = acc[0] * x + acc[1] * y + acc[2]  * z + acc[3]  + trans[b * 3 + 0];
  op[1] = acc[4] * x + acc[5] * y + acc[6]  * z + acc[7]  + trans[b * 3 + 1];
  op[2] = acc[8] * x + acc[9] * y + acc[10] * z + acc[11] + trans[b * 3 + 2];
}

extern "C" void kernel_launch(void* const* d_in, const int* in_sizes, int n_in,
                              void* d_out, int out_size, void* d_ws, size_t ws_size,
                              hipStream_t stream) {
  const float* T_hat   = (const float*)d_in[0];
  const float* J_hat   = (const float*)d_in[1];
  const float* weights = (const float*)d_in[2];
  const float* pose    = (const float*)d_in[3];
  const float* trans   = (const float*)d_in[4];
  float* out = (float*)d_out;

  const int V = in_sizes[0] / 3;   // 6890
  const int B = in_sizes[3] / 72;  // 512

  const int nvchunks = (V + TPB - 1) / TPB;  // 27

  const size_t ws_needed = (size_t)B * NJ * 12 * sizeof(float);  // 576 KB
  if (ws_size >= ws_needed && (B % BPT) == 0) {
    float* Gws = (float*)d_ws;
    const int fkblocks = (B + FK_BPB - 1) / FK_BPB;  // 64
    smpl_fk_kernel<<<fkblocks, FK_BPB * 32, 0, stream>>>(J_hat, pose, Gws, B);
    dim3 grid(nvchunks, B / BPT);  // (27, 128)
    smpl_blend_ws_kernel<<<grid, TPB, 0, stream>>>(
        T_hat, weights, trans, Gws, out, V);
  } else {
    dim3 grid(nvchunks, B);
    smpl_blend_lds_kernel<<<grid, TPB, 0, stream>>>(
        T_hat, J_hat, weights, pose, trans, out, V);
  }
}